// Round 10
// baseline (307.016 us; speedup 1.0000x reference)
//
#include <hip/hip_runtime.h>

typedef _Float16 half8  __attribute__((ext_vector_type(8)));
typedef _Float16 half4v __attribute__((ext_vector_type(4)));
typedef __fp16   fp16x2 __attribute__((ext_vector_type(2)));   // cvt_pkrtz return type
typedef float    floatx4 __attribute__((ext_vector_type(4)));

#define N_ATOMS 131072
#define NUM_GS  128
#define HIDDEN  512
#define N_MOL   1024

#define BM      64                      // atoms per MLP block
#define NB_SIDE (N_ATOMS / BM)          // 2048 blocks per type-side
#define NT_TOT  (HIDDEN / 16)           // 32 n-tiles in fragment layout
#define SH1_LD  (HIDDEN + 8)            // sH1 leading dim (halves)
#define SGH_LD  (NUM_GS + 8)            // sGh leading dim (halves)

// ---- workspace byte offsets ----
#define WS_CNT_OFF     0               // int[2]
#define WS_MOLSUM_OFF  1024            // float[1024]
#define WS_PERM_OFF    9216            // int[131072]
#define WS_W1FA_OFF    533504          // fp16 frags 512*128
#define WS_W1FB_OFF    664576
#define WS_W2FA_OFF    795648          // fp16 frags 512*512
#define WS_W2FB_OFF    1319936
#define WS_ZERO_BYTES  5120            // cnt + mol_sum

// 5-op tanh: 1 - 2/(exp(2x)+1). Saturates correctly at +/-inf.
__device__ __forceinline__ float fast_tanh(float x) {
    float e = exp2f(x * 2.8853900817779268f);   // exp(2x)
    float r = __builtin_amdgcn_rcpf(e + 1.0f);
    return fmaf(-2.0f, r, 1.0f);
}

// ---------------------------------------------------------------------------
// Fused prep kernel (unchanged):
//  blocks [0,512)  : partition atoms by type, 2 global atomics per block.
//  blocks [512,832): pack W1/W2 fp32 [K][512] -> fp16 MFMA B-fragment layout
//                    [ktile][ntile][lane][8] (coalesced 1KB loads in mlp).
// ---------------------------------------------------------------------------
__global__ __launch_bounds__(256)
void prep_kernel(const int* __restrict__ types,
                 const float* __restrict__ W1A, const float* __restrict__ W1B,
                 const float* __restrict__ W2A, const float* __restrict__ W2B,
                 int* __restrict__ cnt, int* __restrict__ perm,
                 _Float16* __restrict__ W1FA, _Float16* __restrict__ W1FB,
                 _Float16* __restrict__ W2FA, _Float16* __restrict__ W2FB) {
    __shared__ float tile[32][65];
    const int p   = blockIdx.x;
    const int tid = threadIdx.x;

    if (p < 512) {                      // ---- partition, 2 atomics/block ----
        __shared__ int sCA[4];
        __shared__ int sBaseA, sBaseB;
        const int i    = p * 256 + tid;
        const int lane = tid & 63;
        const int w    = tid >> 6;
        const bool isA = (types[i] == 0);
        unsigned long long mask = __ballot(isA);
        unsigned long long lt   = ((unsigned long long)1 << lane) - 1;
        int rA = __popcll(mask & lt);
        if (lane == 0) sCA[w] = __popcll(mask);
        __syncthreads();
        if (tid == 0) {
            int tot = sCA[0] + sCA[1] + sCA[2] + sCA[3];
            sBaseA = atomicAdd(&cnt[0], tot);
            sBaseB = atomicAdd(&cnt[1], 256 - tot);
        }
        __syncthreads();
        int preA = 0;
        #pragma unroll
        for (int k = 0; k < 4; ++k) preA += (k < w) ? sCA[k] : 0;
        int preB = w * 64 - preA;
        int rB   = lane - rA;
        if (isA) perm[sBaseA + preA + rA] = i;
        else     perm[N_ATOMS - 1 - (sBaseB + preB + rB)] = i;
        return;
    }

    // ---- weight pack: block handles K=32 x N=64 region ----
    const float* src; _Float16* dst; int pb;
    if (p < 544)      { src = W1A; dst = W1FA; pb = p - 512; }
    else if (p < 576) { src = W1B; dst = W1FB; pb = p - 544; }
    else if (p < 704) { src = W2A; dst = W2FA; pb = p - 576; }
    else              { src = W2B; dst = W2FB; pb = p - 704; }
    const int bx = pb & 7;
    const int by = pb >> 3;
    const int n0 = bx * 64, k0 = by * 32;
    #pragma unroll
    for (int i = 0; i < 8; ++i) {
        int idx = tid + i * 256;
        int r = idx >> 6, c = idx & 63;
        tile[r][c] = src[(size_t)(k0 + r) * HIDDEN + n0 + c];
    }
    __syncthreads();
    const int nt_l = tid >> 6, lane = tid & 63;
    const int l15 = lane & 15, q = lane >> 4;
    half8 v;
    #pragma unroll
    for (int j = 0; j < 8; ++j)
        v[j] = (_Float16)tile[q * 8 + j][nt_l * 16 + l15];
    const int ntile = bx * 4 + nt_l;
    *(half8*)(dst + (((size_t)by * NT_TOT + ntile) * 64 + lane) * 8) = v;
}

// ---------------------------------------------------------------------------
// Fused per-type MLP, f16 MFMA. Round-10: BM=64, 512 threads (8 waves).
// Wave w owns n-tiles [4w, 4w+4) (64 cols) for ALL 64 atoms -> acc[4][4]
// = 64 VGPRs (same as R9) and ZERO duplicate B-fragment loads: per-block
// L2 weight traffic is unchanged (640 KB) while atoms/block doubles ->
// total L2 stream halves (2.6 GB -> 1.3 GB, the R9 bottleneck term).
// sGh is ALIASED into sH1's buffer (sGh dies once layer-1 MFMAs finish;
// extra barrier separates last sGh read from epilogue write). LDS ~67 KB
// -> 2 blocks/CU = 16 waves/CU (up from 12).
// ---------------------------------------------------------------------------
__global__ __launch_bounds__(512, 4)
void mlp_kernel(const float* __restrict__ Gs,
                const int*   __restrict__ mol_id,
                const _Float16* __restrict__ W1FA, const _Float16* __restrict__ W2FA,
                const float* __restrict__ b1A, const float* __restrict__ b2A,
                const float* __restrict__ W3A, const float* __restrict__ b3A,
                const float* __restrict__ offA,
                const _Float16* __restrict__ W1FB, const _Float16* __restrict__ W2FB,
                const float* __restrict__ b1B, const float* __restrict__ b2B,
                const float* __restrict__ W3B, const float* __restrict__ b3B,
                const float* __restrict__ offB,
                const int* __restrict__ cnt, const int* __restrict__ perm,
                float* __restrict__ mol_sum) {
    // sBuf holds sGh (64 x 136 halves, 17 KB) early, sH1 (64 x 520, 65 KB) late.
    __shared__ __align__(16) _Float16 sBuf[BM * SH1_LD];
    __shared__ int   sOrig[BM];
    __shared__ float sPart[8][BM];

    _Float16 (*sH1)[SH1_LD] = (_Float16(*)[SH1_LD])sBuf;
    _Float16 (*sGh)[SGH_LD] = (_Float16(*)[SGH_LD])sBuf;

    const int b     = blockIdx.x;
    const int nA    = cnt[0];
    const int sideB = (b >= NB_SIDE) ? 1 : 0;
    const int r0    = (sideB ? b - NB_SIDE : b) * BM;
    const int nSide = sideB ? (N_ATOMS - nA) : nA;
    if (r0 >= nSide) return;

    const _Float16 *W1F, *W2F;
    const float *b1, *b2, *W3;
    float b3off;
    if (!sideB) { W1F = W1FA; W2F = W2FA; b1 = b1A; b2 = b2A; W3 = W3A; b3off = b3A[0] + offA[0]; }
    else        { W1F = W1FB; W2F = W2FB; b1 = b1B; b2 = b2B; W3 = W3B; b3off = b3B[0] + offB[0]; }

    const int tid = threadIdx.x;
    if (tid < BM) {
        int r = r0 + tid;
        int orig = -1;
        if (r < nSide) orig = sideB ? perm[N_ATOMS - 1 - r] : perm[r];
        sOrig[tid] = orig;
    }
    __syncthreads();

    // ---- stage G tile (fp32 -> fp16 via pkrtz): 64 rows x 128 cols = 2048 float4
    #pragma unroll
    for (int i = 0; i < 4; ++i) {
        int idx = tid + 512 * i;
        int row = idx >> 5;             // 32 float4 per row
        int c4  = idx & 31;
        int orig = sOrig[row];
        float4 v = make_float4(0.f, 0.f, 0.f, 0.f);
        if (orig >= 0) v = ((const float4*)(Gs + (size_t)orig * NUM_GS))[c4];
        union { half4v h4; fp16x2 h2[2]; } hu;
        hu.h2[0] = __builtin_amdgcn_cvt_pkrtz(v.x, v.y);
        hu.h2[1] = __builtin_amdgcn_cvt_pkrtz(v.z, v.w);
        *(half4v*)&sGh[row][c4 * 4] = hu.h4;
    }
    __syncthreads();

    const int lane = tid & 63;
    const int wid  = tid >> 6;          // wave owns n-tiles [4*wid, 4*wid+4)
    const int l15  = lane & 15;
    const int quad = lane >> 4;

    floatx4 acc[4][4];
    #pragma unroll
    for (int mt = 0; mt < 4; ++mt)
        #pragma unroll
        for (int nt = 0; nt < 4; ++nt) acc[mt][nt] = (floatx4){0.f, 0.f, 0.f, 0.f};

    // ================= layer 1: H1 = tanh(G @ W1 + b1), K=128 =================
    #pragma unroll
    for (int ks = 0; ks < NUM_GS / 32; ++ks) {
        half8 a[4];
        #pragma unroll
        for (int mt = 0; mt < 4; ++mt)
            a[mt] = *(const half8*)&sGh[mt * 16 + l15][ks * 32 + quad * 8];
        #pragma unroll
        for (int nt = 0; nt < 4; ++nt) {
            int ntile = wid * 4 + nt;
            half8 bf = *(const half8*)(W1F + (((size_t)ks * NT_TOT + ntile) * 64 + lane) * 8);
            #pragma unroll
            for (int mt = 0; mt < 4; ++mt)
                acc[mt][nt] = __builtin_amdgcn_mfma_f32_16x16x32_f16(a[mt], bf, acc[mt][nt], 0, 0, 0);
        }
    }
    __syncthreads();                    // all waves done reading sGh (aliased with sH1)

    #pragma unroll
    for (int nt = 0; nt < 4; ++nt) {
        int col = wid * 64 + nt * 16 + l15;
        float b1v = b1[col];
        #pragma unroll
        for (int mt = 0; mt < 4; ++mt)
            #pragma unroll
            for (int r = 0; r < 4; ++r)
                sH1[mt * 16 + quad * 4 + r][col] = (_Float16)fast_tanh(acc[mt][nt][r] + b1v);
    }
    __syncthreads();

    // ================= layer 2: pre2 = H1 @ W2 + b2, K=512 =================
    #pragma unroll
    for (int mt = 0; mt < 4; ++mt)
        #pragma unroll
        for (int nt = 0; nt < 4; ++nt) acc[mt][nt] = (floatx4){0.f, 0.f, 0.f, 0.f};

    #pragma unroll 4
    for (int ks = 0; ks < HIDDEN / 32; ++ks) {
        half8 a[4];
        #pragma unroll
        for (int mt = 0; mt < 4; ++mt)
            a[mt] = *(const half8*)&sH1[mt * 16 + l15][ks * 32 + quad * 8];
        #pragma unroll
        for (int nt = 0; nt < 4; ++nt) {
            int ntile = wid * 4 + nt;
            half8 bf = *(const half8*)(W2F + (((size_t)ks * NT_TOT + ntile) * 64 + lane) * 8);
            #pragma unroll
            for (int mt = 0; mt < 4; ++mt)
                acc[mt][nt] = __builtin_amdgcn_mfma_f32_16x16x32_f16(a[mt], bf, acc[mt][nt], 0, 0, 0);
        }
    }

    // ======== layer 3 fused: e = sum_j tanh(pre2_j)*W3_j + b3 + off ========
    float p[4][4];
    #pragma unroll
    for (int mt = 0; mt < 4; ++mt)
        #pragma unroll
        for (int r = 0; r < 4; ++r) p[mt][r] = 0.f;

    #pragma unroll
    for (int nt = 0; nt < 4; ++nt) {
        int col = wid * 64 + nt * 16 + l15;
        float b2v = b2[col];
        float w3v = W3[col];
        #pragma unroll
        for (int mt = 0; mt < 4; ++mt)
            #pragma unroll
            for (int r = 0; r < 4; ++r) {
                float t = fast_tanh(acc[mt][nt][r] + b2v);
                p[mt][r] = fmaf(t, w3v, p[mt][r]);
            }
    }
    #pragma unroll
    for (int mt = 0; mt < 4; ++mt)
        #pragma unroll
        for (int r = 0; r < 4; ++r) {
            float v = p[mt][r];
            v += __shfl_xor(v, 1, 64);
            v += __shfl_xor(v, 2, 64);
            v += __shfl_xor(v, 4, 64);
            v += __shfl_xor(v, 8, 64);
            p[mt][r] = v;
        }
    if (l15 == 0) {
        #pragma unroll
        for (int mt = 0; mt < 4; ++mt)
            #pragma unroll
            for (int r = 0; r < 4; ++r)
                sPart[wid][mt * 16 + quad * 4 + r] = p[mt][r];
    }
    __syncthreads();
    if (tid < BM) {
        int orig = sOrig[tid];
        if (orig >= 0) {
            float e = b3off;
            #pragma unroll
            for (int w = 0; w < 8; ++w) e += sPart[w][tid];
            atomicAdd(&mol_sum[mol_id[orig]], e);
        }
    }
}

// ---------------------------------------------------------------------------
// finalize: per-molecule mean; counts via binary search in sorted mol_id.
// ---------------------------------------------------------------------------
__global__ void finalize_kernel(const float* __restrict__ mol_sum,
                                const int* __restrict__ mol_id,
                                float* __restrict__ out) {
    int m = blockIdx.x * blockDim.x + threadIdx.x;
    if (m >= N_MOL) return;
    int lo0 = 0, hi0 = N_ATOMS;
    while (lo0 < hi0) { int mid = (lo0 + hi0) >> 1; if (mol_id[mid] < m) lo0 = mid + 1; else hi0 = mid; }
    int lo1 = lo0, hi1 = N_ATOMS;
    while (lo1 < hi1) { int mid = (lo1 + hi1) >> 1; if (mol_id[mid] < m + 1) lo1 = mid + 1; else hi1 = mid; }
    float c = (float)(lo1 - lo0);
    out[m] = mol_sum[m] / fmaxf(c, 1.0f);
}

extern "C" void kernel_launch(void* const* d_in, const int* in_sizes, int n_in,
                              void* d_out, int out_size, void* d_ws, size_t ws_size,
                              hipStream_t stream) {
    const float* Gs     = (const float*)d_in[0];
    const int*   types  = (const int*)d_in[1];
    const int*   mol_id = (const int*)d_in[2];
    const float* W1A = (const float*)d_in[3];
    const float* b1A = (const float*)d_in[4];
    const float* W2A = (const float*)d_in[5];
    const float* b2A = (const float*)d_in[6];
    const float* W3A = (const float*)d_in[7];
    const float* b3A = (const float*)d_in[8];
    const float* oA  = (const float*)d_in[9];
    const float* W1B = (const float*)d_in[10];
    const float* b1B = (const float*)d_in[11];
    const float* W2B = (const float*)d_in[12];
    const float* b2B = (const float*)d_in[13];
    const float* W3B = (const float*)d_in[14];
    const float* b3B = (const float*)d_in[15];
    const float* oB  = (const float*)d_in[16];

    char* ws = (char*)d_ws;
    int*      cnt     = (int*)(ws + WS_CNT_OFF);
    float*    mol_sum = (float*)(ws + WS_MOLSUM_OFF);
    int*      perm    = (int*)(ws + WS_PERM_OFF);
    _Float16* W1FA    = (_Float16*)(ws + WS_W1FA_OFF);
    _Float16* W1FB    = (_Float16*)(ws + WS_W1FB_OFF);
    _Float16* W2FA    = (_Float16*)(ws + WS_W2FA_OFF);
    _Float16* W2FB    = (_Float16*)(ws + WS_W2FB_OFF);
    float* out = (float*)d_out;

    hipMemsetAsync(d_ws, 0, WS_ZERO_BYTES, stream);
    prep_kernel<<<832, 256, 0, stream>>>(types, W1A, W1B, W2A, W2B,
                                         cnt, perm,
                                         W1FA, W1FB, W2FA, W2FB);
    mlp_kernel<<<2 * NB_SIDE, 512, 0, stream>>>(
        Gs, mol_id,
        W1FA, W2FA, b1A, b2A, W3A, b3A, oA,
        W1FB, W2FB, b1B, b2B, W3B, b3B, oB,
        cnt, perm, mol_sum);
    finalize_kernel<<<(N_MOL + 255) / 256, 256, 0, stream>>>(mol_sum, mol_id, out);
}

// Round 11
// 275.798 us; speedup vs baseline: 1.1132x; 1.1132x over previous
//
#include <hip/hip_runtime.h>

typedef _Float16 half8  __attribute__((ext_vector_type(8)));
typedef _Float16 half4v __attribute__((ext_vector_type(4)));
typedef __fp16   fp16x2 __attribute__((ext_vector_type(2)));   // cvt_pkrtz return type
typedef float    floatx4 __attribute__((ext_vector_type(4)));

#define N_ATOMS 131072
#define NUM_GS  128
#define HIDDEN  512
#define N_MOL   1024

#define BM      64                      // atoms per MLP block
#define NB_SIDE (N_ATOMS / BM)          // 2048 blocks per type-side
#define NT_TOT  (HIDDEN / 16)           // 32 n-tiles in fragment layout
#define SH1_LD  (HIDDEN + 8)            // sH1 leading dim (halves)
#define SGH_LD  (NUM_GS + 8)            // sGh leading dim (halves)

// ---- workspace byte offsets ----
#define WS_CNT_OFF     0               // int[2]
#define WS_MOLSUM_OFF  1024            // float[1024]
#define WS_PERM_OFF    9216            // int[131072]
#define WS_W1FA_OFF    533504          // fp16 frags 512*128
#define WS_W1FB_OFF    664576
#define WS_W2FA_OFF    795648          // fp16 frags 512*512
#define WS_W2FB_OFF    1319936
#define WS_ZERO_BYTES  5120            // cnt + mol_sum

// 5-op tanh: 1 - 2/(exp(2x)+1). Saturates correctly at +/-inf.
__device__ __forceinline__ float fast_tanh(float x) {
    float e = exp2f(x * 2.8853900817779268f);   // exp(2x)
    float r = __builtin_amdgcn_rcpf(e + 1.0f);
    return fmaf(-2.0f, r, 1.0f);
}

// ---------------------------------------------------------------------------
// Fused prep kernel (unchanged):
//  blocks [0,512)  : partition atoms by type, 2 global atomics per block.
//  blocks [512,832): pack W1/W2 fp32 [K][512] -> fp16 MFMA B-fragment layout
//                    [ktile][ntile][lane][8] (coalesced 1KB loads in mlp).
// ---------------------------------------------------------------------------
__global__ __launch_bounds__(256)
void prep_kernel(const int* __restrict__ types,
                 const float* __restrict__ W1A, const float* __restrict__ W1B,
                 const float* __restrict__ W2A, const float* __restrict__ W2B,
                 int* __restrict__ cnt, int* __restrict__ perm,
                 _Float16* __restrict__ W1FA, _Float16* __restrict__ W1FB,
                 _Float16* __restrict__ W2FA, _Float16* __restrict__ W2FB) {
    __shared__ float tile[32][65];
    const int p   = blockIdx.x;
    const int tid = threadIdx.x;

    if (p < 512) {                      // ---- partition, 2 atomics/block ----
        __shared__ int sCA[4];
        __shared__ int sBaseA, sBaseB;
        const int i    = p * 256 + tid;
        const int lane = tid & 63;
        const int w    = tid >> 6;
        const bool isA = (types[i] == 0);
        unsigned long long mask = __ballot(isA);
        unsigned long long lt   = ((unsigned long long)1 << lane) - 1;
        int rA = __popcll(mask & lt);
        if (lane == 0) sCA[w] = __popcll(mask);
        __syncthreads();
        if (tid == 0) {
            int tot = sCA[0] + sCA[1] + sCA[2] + sCA[3];
            sBaseA = atomicAdd(&cnt[0], tot);
            sBaseB = atomicAdd(&cnt[1], 256 - tot);
        }
        __syncthreads();
        int preA = 0;
        #pragma unroll
        for (int k = 0; k < 4; ++k) preA += (k < w) ? sCA[k] : 0;
        int preB = w * 64 - preA;
        int rB   = lane - rA;
        if (isA) perm[sBaseA + preA + rA] = i;
        else     perm[N_ATOMS - 1 - (sBaseB + preB + rB)] = i;
        return;
    }

    // ---- weight pack: block handles K=32 x N=64 region ----
    const float* src; _Float16* dst; int pb;
    if (p < 544)      { src = W1A; dst = W1FA; pb = p - 512; }
    else if (p < 576) { src = W1B; dst = W1FB; pb = p - 544; }
    else if (p < 704) { src = W2A; dst = W2FA; pb = p - 576; }
    else              { src = W2B; dst = W2FB; pb = p - 704; }
    const int bx = pb & 7;
    const int by = pb >> 3;
    const int n0 = bx * 64, k0 = by * 32;
    #pragma unroll
    for (int i = 0; i < 8; ++i) {
        int idx = tid + i * 256;
        int r = idx >> 6, c = idx & 63;
        tile[r][c] = src[(size_t)(k0 + r) * HIDDEN + n0 + c];
    }
    __syncthreads();
    const int nt_l = tid >> 6, lane = tid & 63;
    const int l15 = lane & 15, q = lane >> 4;
    half8 v;
    #pragma unroll
    for (int j = 0; j < 8; ++j)
        v[j] = (_Float16)tile[q * 8 + j][nt_l * 16 + l15];
    const int ntile = bx * 4 + nt_l;
    *(half8*)(dst + (((size_t)by * NT_TOT + ntile) * 64 + lane) * 8) = v;
}

// ---------------------------------------------------------------------------
// Fused per-type MLP, f16 MFMA. BM=64, 512 threads (8 waves); wave w owns
// n-tiles [4w, 4w+4) for ALL 64 atoms -> zero duplicate B-fragment loads,
// L2 weight stream halves vs BM=32. sGh aliased into sH1's buffer.
// Round-11: unroll 2 (was 4) on the MFMA K-loops. R10's unroll-4 kept 4
// k-steps of a[4] fragments live (64 regs) + acc 64 -> blew the 128-reg
// combined budget at launch_bounds(512,4) -> scratch spills (WRITE_SIZE
// 73 MB). Live set now ~124 <= 128.
// ---------------------------------------------------------------------------
__global__ __launch_bounds__(512, 4)
void mlp_kernel(const float* __restrict__ Gs,
                const int*   __restrict__ mol_id,
                const _Float16* __restrict__ W1FA, const _Float16* __restrict__ W2FA,
                const float* __restrict__ b1A, const float* __restrict__ b2A,
                const float* __restrict__ W3A, const float* __restrict__ b3A,
                const float* __restrict__ offA,
                const _Float16* __restrict__ W1FB, const _Float16* __restrict__ W2FB,
                const float* __restrict__ b1B, const float* __restrict__ b2B,
                const float* __restrict__ W3B, const float* __restrict__ b3B,
                const float* __restrict__ offB,
                const int* __restrict__ cnt, const int* __restrict__ perm,
                float* __restrict__ mol_sum) {
    // sBuf holds sGh (64 x 136 halves, 17 KB) early, sH1 (64 x 520, 65 KB) late.
    __shared__ __align__(16) _Float16 sBuf[BM * SH1_LD];
    __shared__ int   sOrig[BM];
    __shared__ float sPart[8][BM];

    _Float16 (*sH1)[SH1_LD] = (_Float16(*)[SH1_LD])sBuf;
    _Float16 (*sGh)[SGH_LD] = (_Float16(*)[SGH_LD])sBuf;

    const int b     = blockIdx.x;
    const int nA    = cnt[0];
    const int sideB = (b >= NB_SIDE) ? 1 : 0;
    const int r0    = (sideB ? b - NB_SIDE : b) * BM;
    const int nSide = sideB ? (N_ATOMS - nA) : nA;
    if (r0 >= nSide) return;

    const _Float16 *W1F, *W2F;
    const float *b1, *b2, *W3;
    float b3off;
    if (!sideB) { W1F = W1FA; W2F = W2FA; b1 = b1A; b2 = b2A; W3 = W3A; b3off = b3A[0] + offA[0]; }
    else        { W1F = W1FB; W2F = W2FB; b1 = b1B; b2 = b2B; W3 = W3B; b3off = b3B[0] + offB[0]; }

    const int tid = threadIdx.x;
    if (tid < BM) {
        int r = r0 + tid;
        int orig = -1;
        if (r < nSide) orig = sideB ? perm[N_ATOMS - 1 - r] : perm[r];
        sOrig[tid] = orig;
    }
    __syncthreads();

    // ---- stage G tile (fp32 -> fp16 via pkrtz): 64 rows x 128 cols = 2048 float4
    #pragma unroll
    for (int i = 0; i < 4; ++i) {
        int idx = tid + 512 * i;
        int row = idx >> 5;             // 32 float4 per row
        int c4  = idx & 31;
        int orig = sOrig[row];
        float4 v = make_float4(0.f, 0.f, 0.f, 0.f);
        if (orig >= 0) v = ((const float4*)(Gs + (size_t)orig * NUM_GS))[c4];
        union { half4v h4; fp16x2 h2[2]; } hu;
        hu.h2[0] = __builtin_amdgcn_cvt_pkrtz(v.x, v.y);
        hu.h2[1] = __builtin_amdgcn_cvt_pkrtz(v.z, v.w);
        *(half4v*)&sGh[row][c4 * 4] = hu.h4;
    }
    __syncthreads();

    const int lane = tid & 63;
    const int wid  = tid >> 6;          // wave owns n-tiles [4*wid, 4*wid+4)
    const int l15  = lane & 15;
    const int quad = lane >> 4;

    floatx4 acc[4][4];
    #pragma unroll
    for (int mt = 0; mt < 4; ++mt)
        #pragma unroll
        for (int nt = 0; nt < 4; ++nt) acc[mt][nt] = (floatx4){0.f, 0.f, 0.f, 0.f};

    // ================= layer 1: H1 = tanh(G @ W1 + b1), K=128 =================
    #pragma unroll 2
    for (int ks = 0; ks < NUM_GS / 32; ++ks) {
        half8 a[4];
        #pragma unroll
        for (int mt = 0; mt < 4; ++mt)
            a[mt] = *(const half8*)&sGh[mt * 16 + l15][ks * 32 + quad * 8];
        #pragma unroll
        for (int nt = 0; nt < 4; ++nt) {
            int ntile = wid * 4 + nt;
            half8 bf = *(const half8*)(W1F + (((size_t)ks * NT_TOT + ntile) * 64 + lane) * 8);
            #pragma unroll
            for (int mt = 0; mt < 4; ++mt)
                acc[mt][nt] = __builtin_amdgcn_mfma_f32_16x16x32_f16(a[mt], bf, acc[mt][nt], 0, 0, 0);
        }
    }
    __syncthreads();                    // all waves done reading sGh (aliased with sH1)

    #pragma unroll
    for (int nt = 0; nt < 4; ++nt) {
        int col = wid * 64 + nt * 16 + l15;
        float b1v = b1[col];
        #pragma unroll
        for (int mt = 0; mt < 4; ++mt)
            #pragma unroll
            for (int r = 0; r < 4; ++r)
                sH1[mt * 16 + quad * 4 + r][col] = (_Float16)fast_tanh(acc[mt][nt][r] + b1v);
    }
    __syncthreads();

    // ================= layer 2: pre2 = H1 @ W2 + b2, K=512 =================
    #pragma unroll
    for (int mt = 0; mt < 4; ++mt)
        #pragma unroll
        for (int nt = 0; nt < 4; ++nt) acc[mt][nt] = (floatx4){0.f, 0.f, 0.f, 0.f};

    #pragma unroll 2
    for (int ks = 0; ks < HIDDEN / 32; ++ks) {
        half8 a[4];
        #pragma unroll
        for (int mt = 0; mt < 4; ++mt)
            a[mt] = *(const half8*)&sH1[mt * 16 + l15][ks * 32 + quad * 8];
        #pragma unroll
        for (int nt = 0; nt < 4; ++nt) {
            int ntile = wid * 4 + nt;
            half8 bf = *(const half8*)(W2F + (((size_t)ks * NT_TOT + ntile) * 64 + lane) * 8);
            #pragma unroll
            for (int mt = 0; mt < 4; ++mt)
                acc[mt][nt] = __builtin_amdgcn_mfma_f32_16x16x32_f16(a[mt], bf, acc[mt][nt], 0, 0, 0);
        }
    }

    // ======== layer 3 fused: e = sum_j tanh(pre2_j)*W3_j + b3 + off ========
    float p[4][4];
    #pragma unroll
    for (int mt = 0; mt < 4; ++mt)
        #pragma unroll
        for (int r = 0; r < 4; ++r) p[mt][r] = 0.f;

    #pragma unroll
    for (int nt = 0; nt < 4; ++nt) {
        int col = wid * 64 + nt * 16 + l15;
        float b2v = b2[col];
        float w3v = W3[col];
        #pragma unroll
        for (int mt = 0; mt < 4; ++mt)
            #pragma unroll
            for (int r = 0; r < 4; ++r) {
                float t = fast_tanh(acc[mt][nt][r] + b2v);
                p[mt][r] = fmaf(t, w3v, p[mt][r]);
            }
    }
    #pragma unroll
    for (int mt = 0; mt < 4; ++mt)
        #pragma unroll
        for (int r = 0; r < 4; ++r) {
            float v = p[mt][r];
            v += __shfl_xor(v, 1, 64);
            v += __shfl_xor(v, 2, 64);
            v += __shfl_xor(v, 4, 64);
            v += __shfl_xor(v, 8, 64);
            p[mt][r] = v;
        }
    if (l15 == 0) {
        #pragma unroll
        for (int mt = 0; mt < 4; ++mt)
            #pragma unroll
            for (int r = 0; r < 4; ++r)
                sPart[wid][mt * 16 + quad * 4 + r] = p[mt][r];
    }
    __syncthreads();
    if (tid < BM) {
        int orig = sOrig[tid];
        if (orig >= 0) {
            float e = b3off;
            #pragma unroll
            for (int w = 0; w < 8; ++w) e += sPart[w][tid];
            atomicAdd(&mol_sum[mol_id[orig]], e);
        }
    }
}

// ---------------------------------------------------------------------------
// finalize: per-molecule mean; counts via binary search in sorted mol_id.
// ---------------------------------------------------------------------------
__global__ void finalize_kernel(const float* __restrict__ mol_sum,
                                const int* __restrict__ mol_id,
                                float* __restrict__ out) {
    int m = blockIdx.x * blockDim.x + threadIdx.x;
    if (m >= N_MOL) return;
    int lo0 = 0, hi0 = N_ATOMS;
    while (lo0 < hi0) { int mid = (lo0 + hi0) >> 1; if (mol_id[mid] < m) lo0 = mid + 1; else hi0 = mid; }
    int lo1 = lo0, hi1 = N_ATOMS;
    while (lo1 < hi1) { int mid = (lo1 + hi1) >> 1; if (mol_id[mid] < m + 1) lo1 = mid + 1; else hi1 = mid; }
    float c = (float)(lo1 - lo0);
    out[m] = mol_sum[m] / fmaxf(c, 1.0f);
}

extern "C" void kernel_launch(void* const* d_in, const int* in_sizes, int n_in,
                              void* d_out, int out_size, void* d_ws, size_t ws_size,
                              hipStream_t stream) {
    const float* Gs     = (const float*)d_in[0];
    const int*   types  = (const int*)d_in[1];
    const int*   mol_id = (const int*)d_in[2];
    const float* W1A = (const float*)d_in[3];
    const float* b1A = (const float*)d_in[4];
    const float* W2A = (const float*)d_in[5];
    const float* b2A = (const float*)d_in[6];
    const float* W3A = (const float*)d_in[7];
    const float* b3A = (const float*)d_in[8];
    const float* oA  = (const float*)d_in[9];
    const float* W1B = (const float*)d_in[10];
    const float* b1B = (const float*)d_in[11];
    const float* W2B = (const float*)d_in[12];
    const float* b2B = (const float*)d_in[13];
    const float* W3B = (const float*)d_in[14];
    const float* b3B = (const float*)d_in[15];
    const float* oB  = (const float*)d_in[16];

    char* ws = (char*)d_ws;
    int*      cnt     = (int*)(ws + WS_CNT_OFF);
    float*    mol_sum = (float*)(ws + WS_MOLSUM_OFF);
    int*      perm    = (int*)(ws + WS_PERM_OFF);
    _Float16* W1FA    = (_Float16*)(ws + WS_W1FA_OFF);
    _Float16* W1FB    = (_Float16*)(ws + WS_W1FB_OFF);
    _Float16* W2FA    = (_Float16*)(ws + WS_W2FA_OFF);
    _Float16* W2FB    = (_Float16*)(ws + WS_W2FB_OFF);
    float* out = (float*)d_out;

    hipMemsetAsync(d_ws, 0, WS_ZERO_BYTES, stream);
    prep_kernel<<<832, 256, 0, stream>>>(types, W1A, W1B, W2A, W2B,
                                         cnt, perm,
                                         W1FA, W1FB, W2FA, W2FB);
    mlp_kernel<<<2 * NB_SIDE, 512, 0, stream>>>(
        Gs, mol_id,
        W1FA, W2FA, b1A, b2A, W3A, b3A, oA,
        W1FB, W2FB, b1B, b2B, W3B, b3B, oB,
        cnt, perm, mol_sum);
    finalize_kernel<<<(N_MOL + 255) / 256, 256, 0, stream>>>(mol_sum, mol_id, out);
}